// Round 17
// baseline (296.833 us; speedup 1.0000x reference)
//
#include <hip/hip_runtime.h>
#include <hip/hip_bf16.h>

#define BATCH 16384
#define HDIM  1024
#define K1    2048

typedef __attribute__((ext_vector_type(4))) float f32x4;
typedef __attribute__((ext_vector_type(4))) int i32x4;

__device__ __forceinline__ unsigned short f2bf(float f) {
  union { float f; unsigned u; } v; v.f = f;
  unsigned r = v.u + 0x7FFFu + ((v.u >> 16) & 1u);
  return (unsigned short)(r >> 16);
}
__device__ __forceinline__ float bf2f(unsigned short h) {
  union { unsigned u; float f; } v; v.u = ((unsigned)h) << 16; return v.f;
}
__device__ __forceinline__ float sigmoidf_(float x) {
  return 1.0f / (1.0f + __builtin_amdgcn_exp2f(x * -1.4426950408889634f));
}
__device__ __forceinline__ float tanhf_(float x) {
  float xc = fminf(fmaxf(x, -8.0f), 8.0f);
  float e = __builtin_amdgcn_exp2f(xc * 2.8853900817779268f);
  return (e - 1.0f) / (e + 1.0f);
}
__device__ __forceinline__ void async16(const void* g, void* l) {
  __builtin_amdgcn_global_load_lds((const __attribute__((address_space(1))) void*)g,
                                   (__attribute__((address_space(3))) void*)l, 16, 0, 0);
}
__device__ __forceinline__ int q8p(float4 v, float s) {
  int a = __float2int_rn(fminf(fmaxf(v.x * s, -127.f), 127.f));
  int b = __float2int_rn(fminf(fmaxf(v.y * s, -127.f), 127.f));
  int c = __float2int_rn(fminf(fmaxf(v.z * s, -127.f), 127.f));
  int d = __float2int_rn(fminf(fmaxf(v.w * s, -127.f), 127.f));
  return (a & 255) | ((b & 255) << 8) | ((c & 255) << 16) | ((d & 255) << 24);
}

#define QXS (127.0f / 6.0f)
#define QWS (127.0f / 0.03125f)
#define SXW ((6.0f / 127.0f) * (0.03125f / 127.0f))

// ---- merged conversion: U8 (i8 [x|y] 16384x2048), W8 (i8 permuted Wcat
//      3072x2048), Wz8 (i8 [Wz|Wih_2H] 1024x2048) ----
// Wcat n' = bn*192 + w*48 + c*16 + i -> chunk c of h = bn*64 + w*16 + i
__global__ void k_conv(const float* __restrict__ x, const float* __restrict__ y,
                       const float* __restrict__ Wih, const float* __restrict__ Whh,
                       const float* __restrict__ Wz,
                       char* __restrict__ U8, char* __restrict__ W8,
                       char* __restrict__ Wz8) {
  const int stride = gridDim.x * blockDim.x;
  const int tid0 = blockIdx.x * blockDim.x + threadIdx.x;
  const int totalU = BATCH * (HDIM / 4);
  for (int q = tid0; q < totalU; q += stride) {
    int b = q >> 8;
    int c = (q & 255) << 2;
    float4 xv = *(const float4*)(x + (long)b * HDIM + c);
    float4 yv = *(const float4*)(y + (long)b * HDIM + c);
    *(int*)(U8 + (long)b * K1 + c) = q8p(xv, QXS);
    *(int*)(U8 + (long)b * K1 + HDIM + c) = q8p(yv, QXS);
  }
  const int totalW = 3072 * (K1 / 4);
  for (int q = tid0; q < totalW; q += stride) {
    int np = q >> 9;
    int kb = (q & 511) << 2;
    int bn = np / 192; int r = np - bn * 192;
    int w = r / 48; int r2 = r - w * 48;
    int c = r2 >> 4, i = r2 & 15;
    int h = bn * 64 + w * 16 + i;
    float4 v;
    if (kb < HDIM) {
      int row = (c == 0) ? h : (c == 1) ? (HDIM + h) : (3 * HDIM + h);
      v = *(const float4*)(Wih + (long)row * HDIM + kb);
    } else {
      int row = (c == 0) ? h : (c == 1) ? (HDIM + h) : (2 * HDIM + h);
      v = *(const float4*)(Whh + (long)row * HDIM + (kb - HDIM));
    }
    *(int*)(W8 + (long)np * K1 + kb) = q8p(v, QWS);
  }
  const int totalZ = HDIM * (K1 / 4);
  for (int q = tid0; q < totalZ; q += stride) {
    int n = q >> 9;
    int kb = (q & 511) << 2;
    float4 v = (kb < HDIM) ? *(const float4*)(Wz + (long)n * HDIM + kb)
                           : *(const float4*)(Wih + (long)(2 * HDIM + n) * HDIM + (kb - HDIM));
    *(int*)(Wz8 + (long)n * K1 + kb) = q8p(v, QWS);
  }
}

// ===== gemm1: i8 128x192 tile, 8 waves (2M x 4N), ring-3, 2 blocks/CU =====
// Per-wave 64x48 -> acc[4][3] = 48 AGPR; unified regs ~110 < 128 so
// __launch_bounds__(512,4) gives 4 waves/SIMD = 16 waves/CU (2 blocks).
// Two independent blocks out-of-phase: one block's 12-MFMA cluster covers
// the other's ds_read/stage/barrier window (m114 co-issue).
// Ring-3 (60KB: 3 x {A 8KB + B 12KB}), stage distance 2:
//   stage(kt+2) -> buf (kt-1)%3, whose reads drained at barrier(kt-1) via
//   per-wave lgkm(0) (stage issues post-barrier) -> overwrite-safe.
// Counted vmcnt: steady leaves stage(kt+2) in flight (lo 3 / hi 2 loads),
// forcing stage(kt+1) landed before barrier(kt); tail vmcnt(0) at NT-2.
// XOR swizzle slot=row&7 via inverse-swizzled global source (0 conflicts).
__global__ __launch_bounds__(512, 4) void k_gemm1(
    const char* __restrict__ U8, const char* __restrict__ W8,
    const float* __restrict__ z, const float* __restrict__ dtp,
    const float* __restrict__ bih, const float* __restrict__ bhh,
    const float* __restrict__ Wdt, const float* __restrict__ bdt,
    float* __restrict__ out, char* __restrict__ zn8,
    unsigned short* __restrict__ sbb) {
  __shared__ char lds[61440];  // 3 x 20480 (A 8KB | B 12KB)
  constexpr int TSZ = 20480;
  const int bid = blockIdx.x;
  const int sid = (bid & 7) * 256 + (bid >> 3);  // XCD-bijective (2048 % 8 == 0)
  const int bm = sid >> 4, bn = sid & 15;
  const long arow0 = (long)bm * 128, brow0 = (long)bn * 192;
  constexpr int NT = 32;

  const int t = threadIdx.x, lane = t & 63, wv = t >> 6;
  const int wm = wv >> 2, wn = wv & 3;
  const int rA = lane & 15;
  const int cphys = ((lane >> 4) << 4) ^ (((rA >> 1) & 3) << 4);
  const int t16 = t * 16;
  const bool blo = (t < 256);

  // A staging (8KB tile = 1 load/thread), inverse-swizzled source
  const int sA = t16 ^ (((t16 >> 7) & 3) << 4);
  const char* pAa = U8 + (arow0 + (sA >> 6)) * (long)K1 + (sA & 63);

  // B staging (12KB): lo waves 2 loads (L=t16, t16+4096), hi 1 (L=t16+4096)
  const int Lb0 = blo ? t16 : t16 + 4096;
  const int Lb1 = t16 + 4096;
  const int sB0 = Lb0 ^ (((Lb0 >> 7) & 3) << 4);
  const int sB1 = Lb1 ^ (((Lb1 >> 7) & 3) << 4);
  const char* pBg0 = W8 + (brow0 + (sB0 >> 6)) * (long)K1 + (sB0 & 63);
  const char* pBg1 = W8 + (brow0 + (sB1 >> 6)) * (long)K1 + (sB1 & 63);

  int offA[4], offB[3];
#pragma unroll
  for (int m = 0; m < 4; ++m)
    offA[m] = (wm * 64 + m * 16 + rA) * 64 + cphys;
#pragma unroll
  for (int n = 0; n < 3; ++n)
    offB[n] = 8192 + (wn * 48 + n * 16 + rA) * 64 + cphys;

#define STAGE_(DST, TT)                                                   \
  do {                                                                    \
    async16(pAa + (long)(TT) * 64, (DST) + t16);                          \
    async16(pBg0 + (long)(TT) * 64, (DST) + 8192 + Lb0);                  \
    if (blo) async16(pBg1 + (long)(TT) * 64, (DST) + 8192 + Lb1);         \
  } while (0)
#define WSTEADY_                                                          \
  do {                                                                    \
    if (blo) asm volatile("s_waitcnt vmcnt(3) lgkmcnt(0)" ::: "memory");  \
    else     asm volatile("s_waitcnt vmcnt(2) lgkmcnt(0)" ::: "memory");  \
  } while (0)
#define WTAIL0_ asm volatile("s_waitcnt vmcnt(0) lgkmcnt(0)" ::: "memory")
#define WLAST_  asm volatile("s_waitcnt lgkmcnt(0)" ::: "memory")

  i32x4 acc[4][3];
#pragma unroll
  for (int m = 0; m < 4; ++m)
#pragma unroll
    for (int n = 0; n < 3; ++n) acc[m][n] = (i32x4)(0);

  // prologue: stage tiles 0,1 into bufs 0,1; force tile 0 landed
  STAGE_(lds, 0);
  STAGE_(lds + TSZ, 1);
  WSTEADY_;
  __builtin_amdgcn_s_barrier();

  const char* rd = lds;
  char* st = lds + 2 * TSZ;
  const char* ldsend = lds + 3 * TSZ;

#pragma unroll 1
  for (int kt = 0; kt < NT; ++kt) {
    i32x4 af_[4], bf_[3];
#pragma unroll
    for (int m = 0; m < 4; ++m) af_[m] = *(const i32x4*)(rd + offA[m]);
#pragma unroll
    for (int n = 0; n < 3; ++n) bf_[n] = *(const i32x4*)(rd + offB[n]);
    if (kt < NT - 2) {
      STAGE_(st, kt + 2);
      WSTEADY_;
    } else if (kt == NT - 2) {
      WTAIL0_;
    } else {
      WLAST_;
    }
    __builtin_amdgcn_s_barrier();
    __builtin_amdgcn_sched_barrier(0);
    __builtin_amdgcn_s_setprio(1);
#pragma unroll
    for (int m = 0; m < 4; ++m)
#pragma unroll
      for (int n = 0; n < 3; ++n)
        acc[m][n] = __builtin_amdgcn_mfma_i32_16x16x64_i8(
            af_[m], bf_[n], acc[m][n], 0, 0, 0);
    __builtin_amdgcn_s_setprio(0);
    rd += TSZ; rd = (rd == ldsend) ? lds : rd;
    st += TSZ; st = (st == ldsend) ? (char*)lds : st;
  }
#undef STAGE_
#undef WSTEADY_
#undef WTAIL0_
#undef WLAST_

  // ---- epilogue: dequant + LEM elementwise ----
  const int q4 = (lane >> 4) << 2;
  const int h = bn * 64 + wn * 16 + rA;
  const int rowbase = bm * 128 + wm * 64;
  const float bi0 = bih[h] + bhh[h];
  const float bi1 = bih[HDIM + h] + bhh[HDIM + h];
  const float bi2 = bih[3 * HDIM + h] + bhh[2 * HDIM + h];
  const float wdt0 = Wdt[0], wdt1 = Wdt[1], bdt0 = bdt[0], bdt1 = bdt[1];
#pragma unroll
  for (int m = 0; m < 4; ++m) {
#pragma unroll
    for (int j = 0; j < 4; ++j) {
      const int b = rowbase + m * 16 + q4 + j;
      const long idx = (long)b * HDIM + h;
      const float dv = dtp[b];
      const float s1 = sigmoidf_(dv * wdt0 + bdt0);
      const float s2 = sigmoidf_(dv * wdt1 + bdt1);
      const float g0 = (float)acc[m][0][j] * SXW + bi0;
      const float g1 = (float)acc[m][1][j] * SXW + bi1;
      const float g2 = (float)acc[m][2][j] * SXW + bi2;
      const float sbar = s1 * sigmoidf_(g0);
      const float s = s2 * sigmoidf_(g1);
      const float zt = tanhf_(g2);
      const float znew = (1.0f - s) * z[idx] + s * zt;
      out[(long)BATCH * HDIM + idx] = znew;  // z_new output (f32)
      int qz = __float2int_rn(fminf(fmaxf(znew * QXS, -127.f), 127.f));
      zn8[idx] = (char)qz;                    // i8 A-half for phase 2
      sbb[idx] = f2bf(sbar);
    }
  }
}

// ===== gemm2: i8 128x256 tile (NB=4), ring-3, KSPLIT=16, 512 blocks =====
// A = [z_new | x]: K-tiles 0-15 from Zn8 (stride 1024), 16-31 from U8's
// x-half (stride 2048), 1 load/thread. B = Wz8 (16KB/tile, 2 loads).
// Stage = 3 uniform loads -> vmcnt steady 3 (leave stage(kt+2)), tail 0.
__global__ __launch_bounds__(512, 4) void k_gemm2(
    const char* __restrict__ Zn8, const char* __restrict__ U8,
    const char* __restrict__ Wz8, const unsigned short* __restrict__ sbb,
    const float* __restrict__ yin, const float* __restrict__ bz,
    float* __restrict__ out) {
  __shared__ char lds[73728];  // 3 x 24576 (A 8KB | B 16KB)
  constexpr int TSZ = 24576;
  const int bid = blockIdx.x;
  const int sid = (bid & 7) * 64 + (bid >> 3);  // 512 % 8 == 0
  const int bm = sid >> 2, bn = sid & 3;
  const long arow0 = (long)bm * 128, brow0 = (long)bn * 256;
  constexpr int NT = 32, KSPLIT = 16;

  const int t = threadIdx.x, lane = t & 63, wv = t >> 6;
  const int wm = wv >> 2, wn = wv & 3;
  const int rA = lane & 15;
  const int cphys = ((lane >> 4) << 4) ^ (((rA >> 1) & 3) << 4);
  const int t16 = t * 16;

  const int sA = t16 ^ (((t16 >> 7) & 3) << 4);
  const char* pZa = Zn8 + (arow0 + (sA >> 6)) * (long)HDIM + (sA & 63);
  const char* pXa = U8 + (arow0 + (sA >> 6)) * (long)K1 + (sA & 63);

  const int Lb0 = t16, Lb1 = t16 + 8192;
  const int sB0 = Lb0 ^ (((Lb0 >> 7) & 3) << 4);
  const int sB1 = Lb1 ^ (((Lb1 >> 7) & 3) << 4);
  const char* pBg0 = Wz8 + (brow0 + (sB0 >> 6)) * (long)K1 + (sB0 & 63);
  const char* pBg1 = Wz8 + (brow0 + (sB1 >> 6)) * (long)K1 + (sB1 & 63);

  int offA[4], offB[4];
#pragma unroll
  for (int m = 0; m < 4; ++m)
    offA[m] = (wm * 64 + m * 16 + rA) * 64 + cphys;
#pragma unroll
  for (int n = 0; n < 4; ++n)
    offB[n] = 8192 + (wn * 64 + n * 16 + rA) * 64 + cphys;

#define STAGE2_(DST, TT)                                                  \
  do {                                                                    \
    if ((TT) < KSPLIT) async16(pZa + (long)(TT) * 64, (DST) + t16);       \
    else async16(pXa + (long)((TT) - KSPLIT) * 64, (DST) + t16);          \
    async16(pBg0 + (long)(TT) * 64, (DST) + 8192 + Lb0);                  \
    async16(pBg1 + (long)(TT) * 64, (DST) + 8192 + Lb1);                  \
  } while (0)
#define W2S_ asm volatile("s_waitcnt vmcnt(3) lgkmcnt(0)" ::: "memory")
#define W2B_ asm volatile("s_waitcnt vmcnt(0) lgkmcnt(0)" ::: "memory")
#define W2C_ asm volatile("s_waitcnt lgkmcnt(0)" ::: "memory")

  i32x4 acc[4][4];
#pragma unroll
  for (int m = 0; m < 4; ++m)
#pragma unroll
    for (int n = 0; n < 4; ++n) acc[m][n] = (i32x4)(0);

  STAGE2_(lds, 0);
  STAGE2_(lds + TSZ, 1);
  W2S_;
  __builtin_amdgcn_s_barrier();

  const char* rd = lds;
  char* st = lds + 2 * TSZ;
  const char* ldsend = lds + 3 * TSZ;

#pragma unroll 1
  for (int kt = 0; kt < NT; ++kt) {
    i32x4 af_[4], bf_[4];
#pragma unroll
    for (int m = 0; m < 4; ++m) af_[m] = *(const i32x4*)(rd + offA[m]);
#pragma unroll
    for (int n = 0; n < 4; ++n) bf_[n] = *(const i32x4*)(rd + offB[n]);
    if (kt < NT - 2) {
      STAGE2_(st, kt + 2);
      W2S_;
    } else if (kt == NT - 2) {
      W2B_;
    } else {
      W2C_;
    }
    __builtin_amdgcn_s_barrier();
    __builtin_amdgcn_sched_barrier(0);
    __builtin_amdgcn_s_setprio(1);
#pragma unroll
    for (int m = 0; m < 4; ++m)
#pragma unroll
      for (int n = 0; n < 4; ++n)
        acc[m][n] = __builtin_amdgcn_mfma_i32_16x16x64_i8(
            af_[m], bf_[n], acc[m][n], 0, 0, 0);
    __builtin_amdgcn_s_setprio(0);
    rd += TSZ; rd = (rd == ldsend) ? lds : rd;
    st += TSZ; st = (st == ldsend) ? (char*)lds : st;
  }
#undef STAGE2_
#undef W2S_
#undef W2B_
#undef W2C_

  // ---- epilogue: dequant + y_new ----
  const int q4 = (lane >> 4) << 2;
  const int rowbase = bm * 128 + wm * 64;
#pragma unroll
  for (int n = 0; n < 4; ++n) {
    const int hc = bn * 256 + wn * 64 + n * 16 + rA;
    const float bzv = bz[hc];
#pragma unroll
    for (int m = 0; m < 4; ++m) {
#pragma unroll
      for (int j = 0; j < 4; ++j) {
        const int b = rowbase + m * 16 + q4 + j;
        const long idx = (long)b * HDIM + hc;
        const float tv = tanhf_((float)acc[m][n][j] * SXW + bzv);
        const float sb = bf2f(sbb[idx]);
        out[idx] = (1.0f - sb) * yin[idx] + sb * tv;  // y_new
      }
    }
  }
}

extern "C" void kernel_launch(void* const* d_in, const int* in_sizes, int n_in,
                              void* d_out, int out_size, void* d_ws, size_t ws_size,
                              hipStream_t stream) {
  const float* x   = (const float*)d_in[0];
  const float* y   = (const float*)d_in[1];
  const float* z   = (const float*)d_in[2];
  const float* dtp = (const float*)d_in[3];
  const float* Wih = (const float*)d_in[4];
  const float* bih = (const float*)d_in[5];
  const float* Whh = (const float*)d_in[6];
  const float* bhh = (const float*)d_in[7];
  const float* Wz  = (const float*)d_in[8];
  const float* bz  = (const float*)d_in[9];
  const float* Wdt = (const float*)d_in[10];
  const float* bdt = (const float*)d_in[11];

  char* ws = (char*)d_ws;
  char*           U8  = ws;                                  // 33,554,432 B
  char*           W8  = ws + 33554432;                       //  6,291,456 B
  char*           Wz8 = ws + 39845888;                       //  2,097,152 B
  char*           Zn8 = ws + 41943040;                       // 16,777,216 B
  unsigned short* Sbb = (unsigned short*)(ws + 58720256);    // 33,554,432 B -> 92,274,688 B
  float* out = (float*)d_out;

  k_conv<<<2048, 256, 0, stream>>>(x, y, Wih, Whh, Wz, U8, W8, Wz8);
  k_gemm1<<<2048, 512, 0, stream>>>(U8, W8, z, dtp, bih, bhh, Wdt, bdt, out, Zn8, Sbb);
  k_gemm2<<<512, 512, 0, stream>>>(Zn8, U8, Wz8, Sbb, y, bz, out);
}

// Round 18
// 267.640 us; speedup vs baseline: 1.1091x; 1.1091x over previous
//
#include <hip/hip_runtime.h>
#include <hip/hip_bf16.h>

#define BATCH 16384
#define HDIM  1024
#define K1    2048

typedef __attribute__((ext_vector_type(4))) float f32x4;
typedef __attribute__((ext_vector_type(4))) int i32x4;

__device__ __forceinline__ unsigned short f2bf(float f) {
  union { float f; unsigned u; } v; v.f = f;
  unsigned r = v.u + 0x7FFFu + ((v.u >> 16) & 1u);
  return (unsigned short)(r >> 16);
}
__device__ __forceinline__ float bf2f(unsigned short h) {
  union { unsigned u; float f; } v; v.u = ((unsigned)h) << 16; return v.f;
}
__device__ __forceinline__ float sigmoidf_(float x) {
  return 1.0f / (1.0f + __builtin_amdgcn_exp2f(x * -1.4426950408889634f));
}
__device__ __forceinline__ float tanhf_(float x) {
  float xc = fminf(fmaxf(x, -8.0f), 8.0f);
  float e = __builtin_amdgcn_exp2f(xc * 2.8853900817779268f);
  return (e - 1.0f) / (e + 1.0f);
}
__device__ __forceinline__ void async16(const void* g, void* l) {
  __builtin_amdgcn_global_load_lds((const __attribute__((address_space(1))) void*)g,
                                   (__attribute__((address_space(3))) void*)l, 16, 0, 0);
}
__device__ __forceinline__ int q8p(float4 v, float s) {
  int a = __float2int_rn(fminf(fmaxf(v.x * s, -127.f), 127.f));
  int b = __float2int_rn(fminf(fmaxf(v.y * s, -127.f), 127.f));
  int c = __float2int_rn(fminf(fmaxf(v.z * s, -127.f), 127.f));
  int d = __float2int_rn(fminf(fmaxf(v.w * s, -127.f), 127.f));
  return (a & 255) | ((b & 255) << 8) | ((c & 255) << 16) | ((d & 255) << 24);
}

#define QXS (127.0f / 6.0f)
#define QWS (127.0f / 0.03125f)
#define SXW ((6.0f / 127.0f) * (0.03125f / 127.0f))

// ---- merged conversion: U8 (i8 [x|y] 16384x2048), W8 (i8 permuted Wcat
//      3072x2048), Wz8 (i8 [Wz|Wih_2H] 1024x2048) ----
// Wcat n' = bn*192 + w*48 + c*16 + i -> chunk c of h = bn*64 + w*16 + i
__global__ void k_conv(const float* __restrict__ x, const float* __restrict__ y,
                       const float* __restrict__ Wih, const float* __restrict__ Whh,
                       const float* __restrict__ Wz,
                       char* __restrict__ U8, char* __restrict__ W8,
                       char* __restrict__ Wz8) {
  const int stride = gridDim.x * blockDim.x;
  const int tid0 = blockIdx.x * blockDim.x + threadIdx.x;
  const int totalU = BATCH * (HDIM / 4);
  for (int q = tid0; q < totalU; q += stride) {
    int b = q >> 8;
    int c = (q & 255) << 2;
    float4 xv = *(const float4*)(x + (long)b * HDIM + c);
    float4 yv = *(const float4*)(y + (long)b * HDIM + c);
    *(int*)(U8 + (long)b * K1 + c) = q8p(xv, QXS);
    *(int*)(U8 + (long)b * K1 + HDIM + c) = q8p(yv, QXS);
  }
  const int totalW = 3072 * (K1 / 4);
  for (int q = tid0; q < totalW; q += stride) {
    int np = q >> 9;
    int kb = (q & 511) << 2;
    int bn = np / 192; int r = np - bn * 192;
    int w = r / 48; int r2 = r - w * 48;
    int c = r2 >> 4, i = r2 & 15;
    int h = bn * 64 + w * 16 + i;
    float4 v;
    if (kb < HDIM) {
      int row = (c == 0) ? h : (c == 1) ? (HDIM + h) : (3 * HDIM + h);
      v = *(const float4*)(Wih + (long)row * HDIM + kb);
    } else {
      int row = (c == 0) ? h : (c == 1) ? (HDIM + h) : (2 * HDIM + h);
      v = *(const float4*)(Whh + (long)row * HDIM + (kb - HDIM));
    }
    *(int*)(W8 + (long)np * K1 + kb) = q8p(v, QWS);
  }
  const int totalZ = HDIM * (K1 / 4);
  for (int q = tid0; q < totalZ; q += stride) {
    int n = q >> 9;
    int kb = (q & 511) << 2;
    float4 v = (kb < HDIM) ? *(const float4*)(Wz + (long)n * HDIM + kb)
                           : *(const float4*)(Wih + (long)(2 * HDIM + n) * HDIM + (kb - HDIM));
    *(int*)(Wz8 + (long)n * K1 + kb) = q8p(v, QWS);
  }
}

// ===== gemm1: i8 128x192 tile, 8 waves (2M x 4N), ring-3, 2 blocks/CU =====
// (R17 config — measured 164 us, best.)
__global__ __launch_bounds__(512, 4) void k_gemm1(
    const char* __restrict__ U8, const char* __restrict__ W8,
    const float* __restrict__ z, const float* __restrict__ dtp,
    const float* __restrict__ bih, const float* __restrict__ bhh,
    const float* __restrict__ Wdt, const float* __restrict__ bdt,
    float* __restrict__ out, char* __restrict__ zn8,
    unsigned short* __restrict__ sbb) {
  __shared__ char lds[61440];  // 3 x 20480 (A 8KB | B 12KB)
  constexpr int TSZ = 20480;
  const int bid = blockIdx.x;
  const int sid = (bid & 7) * 256 + (bid >> 3);  // XCD-bijective (2048 % 8 == 0)
  const int bm = sid >> 4, bn = sid & 15;
  const long arow0 = (long)bm * 128, brow0 = (long)bn * 192;
  constexpr int NT = 32;

  const int t = threadIdx.x, lane = t & 63, wv = t >> 6;
  const int wm = wv >> 2, wn = wv & 3;
  const int rA = lane & 15;
  const int cphys = ((lane >> 4) << 4) ^ (((rA >> 1) & 3) << 4);
  const int t16 = t * 16;
  const bool blo = (t < 256);

  const int sA = t16 ^ (((t16 >> 7) & 3) << 4);
  const char* pAa = U8 + (arow0 + (sA >> 6)) * (long)K1 + (sA & 63);

  const int Lb0 = blo ? t16 : t16 + 4096;
  const int Lb1 = t16 + 4096;
  const int sB0 = Lb0 ^ (((Lb0 >> 7) & 3) << 4);
  const int sB1 = Lb1 ^ (((Lb1 >> 7) & 3) << 4);
  const char* pBg0 = W8 + (brow0 + (sB0 >> 6)) * (long)K1 + (sB0 & 63);
  const char* pBg1 = W8 + (brow0 + (sB1 >> 6)) * (long)K1 + (sB1 & 63);

  int offA[4], offB[3];
#pragma unroll
  for (int m = 0; m < 4; ++m)
    offA[m] = (wm * 64 + m * 16 + rA) * 64 + cphys;
#pragma unroll
  for (int n = 0; n < 3; ++n)
    offB[n] = 8192 + (wn * 48 + n * 16 + rA) * 64 + cphys;

#define STAGE_(DST, TT)                                                   \
  do {                                                                    \
    async16(pAa + (long)(TT) * 64, (DST) + t16);                          \
    async16(pBg0 + (long)(TT) * 64, (DST) + 8192 + Lb0);                  \
    if (blo) async16(pBg1 + (long)(TT) * 64, (DST) + 8192 + Lb1);         \
  } while (0)
#define WSTEADY_                                                          \
  do {                                                                    \
    if (blo) asm volatile("s_waitcnt vmcnt(3) lgkmcnt(0)" ::: "memory");  \
    else     asm volatile("s_waitcnt vmcnt(2) lgkmcnt(0)" ::: "memory");  \
  } while (0)
#define WTAIL0_ asm volatile("s_waitcnt vmcnt(0) lgkmcnt(0)" ::: "memory")
#define WLAST_  asm volatile("s_waitcnt lgkmcnt(0)" ::: "memory")

  i32x4 acc[4][3];
#pragma unroll
  for (int m = 0; m < 4; ++m)
#pragma unroll
    for (int n = 0; n < 3; ++n) acc[m][n] = (i32x4)(0);

  STAGE_(lds, 0);
  STAGE_(lds + TSZ, 1);
  WSTEADY_;
  __builtin_amdgcn_s_barrier();

  const char* rd = lds;
  char* st = lds + 2 * TSZ;
  const char* ldsend = lds + 3 * TSZ;

#pragma unroll 1
  for (int kt = 0; kt < NT; ++kt) {
    i32x4 af_[4], bf_[3];
#pragma unroll
    for (int m = 0; m < 4; ++m) af_[m] = *(const i32x4*)(rd + offA[m]);
#pragma unroll
    for (int n = 0; n < 3; ++n) bf_[n] = *(const i32x4*)(rd + offB[n]);
    if (kt < NT - 2) {
      STAGE_(st, kt + 2);
      WSTEADY_;
    } else if (kt == NT - 2) {
      WTAIL0_;
    } else {
      WLAST_;
    }
    __builtin_amdgcn_s_barrier();
    __builtin_amdgcn_sched_barrier(0);
    __builtin_amdgcn_s_setprio(1);
#pragma unroll
    for (int m = 0; m < 4; ++m)
#pragma unroll
      for (int n = 0; n < 3; ++n)
        acc[m][n] = __builtin_amdgcn_mfma_i32_16x16x64_i8(
            af_[m], bf_[n], acc[m][n], 0, 0, 0);
    __builtin_amdgcn_s_setprio(0);
    rd += TSZ; rd = (rd == ldsend) ? lds : rd;
    st += TSZ; st = (st == ldsend) ? (char*)lds : st;
  }
#undef STAGE_
#undef WSTEADY_
#undef WTAIL0_
#undef WLAST_

  const int q4 = (lane >> 4) << 2;
  const int h = bn * 64 + wn * 16 + rA;
  const int rowbase = bm * 128 + wm * 64;
  const float bi0 = bih[h] + bhh[h];
  const float bi1 = bih[HDIM + h] + bhh[HDIM + h];
  const float bi2 = bih[3 * HDIM + h] + bhh[2 * HDIM + h];
  const float wdt0 = Wdt[0], wdt1 = Wdt[1], bdt0 = bdt[0], bdt1 = bdt[1];
#pragma unroll
  for (int m = 0; m < 4; ++m) {
#pragma unroll
    for (int j = 0; j < 4; ++j) {
      const int b = rowbase + m * 16 + q4 + j;
      const long idx = (long)b * HDIM + h;
      const float dv = dtp[b];
      const float s1 = sigmoidf_(dv * wdt0 + bdt0);
      const float s2 = sigmoidf_(dv * wdt1 + bdt1);
      const float g0 = (float)acc[m][0][j] * SXW + bi0;
      const float g1 = (float)acc[m][1][j] * SXW + bi1;
      const float g2 = (float)acc[m][2][j] * SXW + bi2;
      const float sbar = s1 * sigmoidf_(g0);
      const float s = s2 * sigmoidf_(g1);
      const float zt = tanhf_(g2);
      const float znew = (1.0f - s) * z[idx] + s * zt;
      out[(long)BATCH * HDIM + idx] = znew;  // z_new output (f32)
      int qz = __float2int_rn(fminf(fmaxf(znew * QXS, -127.f), 127.f));
      zn8[idx] = (char)qz;                    // i8 A-half for phase 2
      sbb[idx] = f2bf(sbar);
    }
  }
}

// ===== gemm2: i8 256x128 core (R16 verbatim — measured ~44 us) =====
// A = [z_new | x]: K-tiles 0-15 from Zn8 (stride 1024), 16-31 from U8's
// x-half (stride 2048). B = Wz8 (128x64B=8KB/tile, 1 uniform load/thread).
// 4-buffer distance-3 ring; stage = 3 loads -> vmcnt 6/3/0.
__global__ __launch_bounds__(512, 2) void k_gemm2(
    const char* __restrict__ Zn8, const char* __restrict__ U8,
    const char* __restrict__ Wz8, const unsigned short* __restrict__ sbb,
    const float* __restrict__ yin, const float* __restrict__ bz,
    float* __restrict__ out) {
  __shared__ char lds[98304];  // A 4x16KB + B 4x8KB
  char* ldsA = lds;
  char* ldsB = lds + 65536;
  const int bid = blockIdx.x;
  const int sid = (bid & 7) * 64 + (bid >> 3);  // 512 % 8 == 0
  const int bm = sid >> 3, bn = sid & 7;
  const long arow0 = (long)bm * 256, brow0 = (long)bn * 128;
  constexpr int NT = 32, KSPLIT = 16;

  const int t = threadIdx.x, lane = t & 63, wv = t >> 6;
  const int wm = wv >> 2, wn = wv & 3;
  const int rA = lane & 15;
  const int cphys = ((lane >> 4) << 4) ^ (((rA >> 1) & 3) << 4);
  const int t16 = t * 16;

  const int sA = t16 ^ (((t16 >> 7) & 3) << 4);
  const int rA0 = sA >> 6, cA0 = sA & 63;
  const char* pZa = Zn8 + (arow0 + rA0) * (long)HDIM + cA0;
  const char* pZb = Zn8 + (arow0 + rA0 + 128) * (long)HDIM + cA0;
  const char* pXa = U8 + (arow0 + rA0) * (long)K1 + cA0;
  const char* pXb = U8 + (arow0 + rA0 + 128) * (long)K1 + cA0;

  const int sB0 = t16 ^ (((t16 >> 7) & 3) << 4);
  const char* pBg0 = Wz8 + (brow0 + (sB0 >> 6)) * (long)K1 + (sB0 & 63);

  int offA[8], offB[2];
#pragma unroll
  for (int m = 0; m < 8; ++m)
    offA[m] = (wm * 128 + m * 16 + rA) * 64 + cphys;
#pragma unroll
  for (int n = 0; n < 2; ++n)
    offB[n] = (wn * 32 + n * 16 + rA) * 64 + cphys;

#define STAGE2_(TT)                                                       \
  do {                                                                    \
    char* ab_ = ldsA + ((TT) & 3) * 16384;                                \
    char* bb_ = ldsB + ((TT) & 3) * 8192;                                 \
    if ((TT) < KSPLIT) {                                                  \
      async16(pZa + (long)(TT) * 64, ab_ + t16);                          \
      async16(pZb + (long)(TT) * 64, ab_ + 8192 + t16);                   \
    } else {                                                              \
      async16(pXa + (long)((TT) - KSPLIT) * 64, ab_ + t16);               \
      async16(pXb + (long)((TT) - KSPLIT) * 64, ab_ + 8192 + t16);        \
    }                                                                     \
    async16(pBg0 + (long)(TT) * 64, bb_ + t16);                           \
  } while (0)
#define W2S_ asm volatile("s_waitcnt vmcnt(6) lgkmcnt(0)" ::: "memory")
#define W2A_ asm volatile("s_waitcnt vmcnt(3) lgkmcnt(0)" ::: "memory")
#define W2B_ asm volatile("s_waitcnt vmcnt(0) lgkmcnt(0)" ::: "memory")
#define W2C_ asm volatile("s_waitcnt lgkmcnt(0)" ::: "memory")

  i32x4 acc[8][2];
#pragma unroll
  for (int m = 0; m < 8; ++m)
#pragma unroll
    for (int n = 0; n < 2; ++n) acc[m][n] = (i32x4)(0);

  STAGE2_(0);
  STAGE2_(1);
  STAGE2_(2);
  W2S_;
  __builtin_amdgcn_s_barrier();

#pragma unroll 1
  for (int kt = 0; kt < NT; ++kt) {
    const char* Ab_ = ldsA + (kt & 3) * 16384;
    const char* Bb_ = ldsB + (kt & 3) * 8192;
    i32x4 af_[8], bf_[2];
#pragma unroll
    for (int m = 0; m < 8; ++m) af_[m] = *(const i32x4*)(Ab_ + offA[m]);
#pragma unroll
    for (int n = 0; n < 2; ++n) bf_[n] = *(const i32x4*)(Bb_ + offB[n]);
    if (kt < NT - 3) {
      STAGE2_(kt + 3);
      W2S_;
    } else if (kt == NT - 3) {
      W2A_;
    } else if (kt == NT - 2) {
      W2B_;
    } else {
      W2C_;
    }
    __builtin_amdgcn_s_barrier();
    __builtin_amdgcn_sched_barrier(0);
    __builtin_amdgcn_s_setprio(1);
#pragma unroll
    for (int m = 0; m < 8; ++m)
#pragma unroll
      for (int n = 0; n < 2; ++n)
        acc[m][n] = __builtin_amdgcn_mfma_i32_16x16x64_i8(
            af_[m], bf_[n], acc[m][n], 0, 0, 0);
    __builtin_amdgcn_s_setprio(0);
  }
#undef STAGE2_
#undef W2S_
#undef W2A_
#undef W2B_
#undef W2C_

  const int q4 = (lane >> 4) << 2;
  const int rowbase = bm * 256 + wm * 128;
#pragma unroll
  for (int n = 0; n < 2; ++n) {
    const int hc = bn * 128 + wn * 32 + n * 16 + rA;
    const float bzv = bz[hc];
#pragma unroll
    for (int m = 0; m < 8; ++m) {
#pragma unroll
      for (int j = 0; j < 4; ++j) {
        const int b = rowbase + m * 16 + q4 + j;
        const long idx = (long)b * HDIM + hc;
        const float tv = tanhf_((float)acc[m][n][j] * SXW + bzv);
        const float sb = bf2f(sbb[idx]);
        out[idx] = (1.0f - sb) * yin[idx] + sb * tv;  // y_new
      }
    }
  }
}

extern "C" void kernel_launch(void* const* d_in, const int* in_sizes, int n_in,
                              void* d_out, int out_size, void* d_ws, size_t ws_size,
                              hipStream_t stream) {
  const float* x   = (const float*)d_in[0];
  const float* y   = (const float*)d_in[1];
  const float* z   = (const float*)d_in[2];
  const float* dtp = (const float*)d_in[3];
  const float* Wih = (const float*)d_in[4];
  const float* bih = (const float*)d_in[5];
  const float* Whh = (const float*)d_in[6];
  const float* bhh = (const float*)d_in[7];
  const float* Wz  = (const float*)d_in[8];
  const float* bz  = (const float*)d_in[9];
  const float* Wdt = (const float*)d_in[10];
  const float* bdt = (const float*)d_in[11];

  char* ws = (char*)d_ws;
  char*           U8  = ws;                                  // 33,554,432 B
  char*           W8  = ws + 33554432;                       //  6,291,456 B
  char*           Wz8 = ws + 39845888;                       //  2,097,152 B
  char*           Zn8 = ws + 41943040;                       // 16,777,216 B
  unsigned short* Sbb = (unsigned short*)(ws + 58720256);    // 33,554,432 B -> 92,274,688 B
  float* out = (float*)d_out;

  k_conv<<<2048, 256, 0, stream>>>(x, y, Wih, Whh, Wz, U8, W8, Wz8);
  k_gemm1<<<2048, 512, 0, stream>>>(U8, W8, z, dtp, bih, bhh, Wdt, bdt, out, Zn8, Sbb);
  k_gemm2<<<512, 512, 0, stream>>>(Zn8, U8, Wz8, Sbb, y, bz, out);
}